// Round 1
// baseline (356.221 us; speedup 1.0000x reference)
//
#include <hip/hip_runtime.h>

// MHA forward: B=4 S=2048 D=1024 H=16 dh=64, fp32 in/out, bf16 MFMA compute.
// Pipeline: cvt(x) -> wT(bf16,transposed) -> GEMM QKV -> V transpose -> flash attn -> GEMM out.

typedef __bf16 bf16x8 __attribute__((ext_vector_type(8)));
typedef float f32x4 __attribute__((ext_vector_type(4)));
typedef unsigned short u16x8 __attribute__((ext_vector_type(8)));

#define SEQ 2048
#define DM 1024
#define NHEAD 16
#define MTOT 8192  // B*S

__device__ __forceinline__ unsigned short f2bf(float f) {
  unsigned u = __builtin_bit_cast(unsigned, f);
  u += 0x7fffu + ((u >> 16) & 1u);  // RNE
  return (unsigned short)(u >> 16);
}

__device__ __forceinline__ void async16(const void* g, void* l) {
  __builtin_amdgcn_global_load_lds(
      (const __attribute__((address_space(1))) void*)g,
      (__attribute__((address_space(3))) void*)l, 16, 0, 0);
}

// ---------------- x fp32 -> bf16 ----------------
__global__ __launch_bounds__(256) void k_cvt(const float* __restrict__ x,
                                             unsigned short* __restrict__ xb) {
  size_t i = ((size_t)blockIdx.x * 256 + threadIdx.x) * 8;
  float4 a = *(const float4*)(x + i);
  float4 b = *(const float4*)(x + i + 4);
  u16x8 o;
  o[0] = f2bf(a.x); o[1] = f2bf(a.y); o[2] = f2bf(a.z); o[3] = f2bf(a.w);
  o[4] = f2bf(b.x); o[5] = f2bf(b.y); o[6] = f2bf(b.z); o[7] = f2bf(b.w);
  *(u16x8*)(xb + i) = o;
}

// ---------------- weight fp32 [K][N] -> bf16 wt [N][K] ----------------
__global__ __launch_bounds__(256) void k_wt(const float* __restrict__ w,
                                            unsigned short* __restrict__ wt) {
  __shared__ float t[64][65];
  int nt = blockIdx.x, kt = blockIdx.y;
  int tx = threadIdx.x & 63, ty = threadIdx.x >> 6;
  for (int i = 0; i < 16; ++i) {
    int r = i * 4 + ty;
    t[r][tx] = w[(size_t)(kt * 64 + r) * DM + nt * 64 + tx];
  }
  __syncthreads();
  for (int i = 0; i < 16; ++i) {
    int r = i * 4 + ty;
    wt[(size_t)(nt * 64 + r) * DM + kt * 64 + tx] = f2bf(t[tx][r]);
  }
}

// ---------------- GEMM: C[8192][1024] = A[8192][1024] * Bt[1024][1024]^T + bias ----------------
// 128x128 tile, BK=64, 4 waves (2x2 of 64x64), 16x16x32 MFMA, swizzled LDS.
__global__ __launch_bounds__(256) void k_gemm(const unsigned short* __restrict__ A,
                                              const unsigned short* __restrict__ Bt,
                                              const float* __restrict__ bias,
                                              unsigned short* __restrict__ Cb,
                                              float* __restrict__ Cf) {
  __shared__ __align__(16) unsigned short As[128 * 64];
  __shared__ __align__(16) unsigned short Bs[128 * 64];
  const int K = DM, N = DM;
  int tid = threadIdx.x, w = tid >> 6, l = tid & 63;
  int g = l >> 4, l15 = l & 15;
  int bm = blockIdx.y * 128, bn = blockIdx.x * 128;
  int wm = (w >> 1) * 64, wn = (w & 1) * 64;
  f32x4 acc[4][4];
  for (int mi = 0; mi < 4; ++mi)
    for (int ni = 0; ni < 4; ++ni)
      for (int e = 0; e < 4; ++e) acc[mi][ni][e] = 0.f;

  int lr8 = l >> 3, lp = l & 7;
  for (int kt = 0; kt < K / 64; ++kt) {
    __syncthreads();
    for (int i = 0; i < 4; ++i) {
      int cs = i * 4 + w;            // chunkset 0..15 (8 rows each)
      int row = cs * 8 + lr8;        // tile row 0..127 ; row&7 == lr8
      int c = lp ^ lr8;              // logical 16B chunk (pre-swizzled source)
      async16(A + (size_t)(bm + row) * K + kt * 64 + c * 8, &As[cs * 512]);
      async16(Bt + (size_t)(bn + row) * K + kt * 64 + c * 8, &Bs[cs * 512]);
    }
    __syncthreads();
    bf16x8 af[4][2];
    for (int mi = 0; mi < 4; ++mi)
      for (int kk = 0; kk < 2; ++kk) {
        int row = wm + mi * 16 + l15;
        af[mi][kk] = *(const bf16x8*)&As[row * 64 + (((kk * 4 + g) ^ (row & 7)) * 8)];
      }
    for (int ni = 0; ni < 4; ++ni) {
      int row = wn + ni * 16 + l15;
      bf16x8 b0 = *(const bf16x8*)&Bs[row * 64 + (((0 + g) ^ (row & 7)) * 8)];
      bf16x8 b1 = *(const bf16x8*)&Bs[row * 64 + (((4 + g) ^ (row & 7)) * 8)];
      for (int mi = 0; mi < 4; ++mi) {
        acc[mi][ni] = __builtin_amdgcn_mfma_f32_16x16x32_bf16(af[mi][0], b0, acc[mi][ni], 0, 0, 0);
        acc[mi][ni] = __builtin_amdgcn_mfma_f32_16x16x32_bf16(af[mi][1], b1, acc[mi][ni], 0, 0, 0);
      }
    }
  }
  float bv[4];
  for (int ni = 0; ni < 4; ++ni) bv[ni] = bias[bn + wn + ni * 16 + l15];
  for (int mi = 0; mi < 4; ++mi)
    for (int ni = 0; ni < 4; ++ni) {
      int col = bn + wn + ni * 16 + l15;
      for (int r = 0; r < 4; ++r) {
        int rowg = bm + wm + mi * 16 + g * 4 + r;  // C/D: col=lane&15, row=(lane>>4)*4+reg
        float v = acc[mi][ni][r] + bv[ni];
        if (Cf) Cf[(size_t)rowg * N + col] = v;
        else    Cb[(size_t)rowg * N + col] = f2bf(v);
      }
    }
}

// ---------------- V [b][s][h*64+d] -> Vt [bh][d][s] ----------------
__global__ __launch_bounds__(256) void k_vt(const unsigned short* __restrict__ V,
                                            unsigned short* __restrict__ Vt) {
  __shared__ __align__(16) unsigned short t[64 * 64];
  int st = blockIdx.x, bh = blockIdx.y;
  int b = bh >> 4, h = bh & 15;
  int tid = threadIdx.x, w = tid >> 6, l = tid & 63;
  for (int i = 0; i < 2; ++i) {
    int cs = i * 4 + w;
    int row = cs * 8 + (l >> 3);
    int c = l & 7;
    async16(V + ((size_t)(b * SEQ + st * 64 + row) * DM + h * 64 + c * 8), &t[cs * 512]);
  }
  __syncthreads();
  for (int p = 0; p < 2; ++p) {
    int d = p * 32 + (tid >> 3);
    int cs = tid & 7;
    u16x8 o;
    for (int j = 0; j < 8; ++j) o[j] = t[(cs * 8 + j) * 64 + d];
    *(u16x8*)(Vt + ((size_t)bh * 64 + d) * SEQ + st * 64 + cs * 8) = o;
  }
}

// ---------------- flash attention ----------------
// grid (16 q-tiles, 64 bh); 4 waves x 32 q-rows; KV tile = 64.
__global__ __launch_bounds__(256) void k_attn(const unsigned short* __restrict__ Q,
                                              const unsigned short* __restrict__ Kg,
                                              const unsigned short* __restrict__ Vt,
                                              unsigned short* __restrict__ Og) {
  __shared__ __align__(16) unsigned short Ks[64 * 64];
  __shared__ __align__(16) unsigned short Vs[64 * 64];
  __shared__ __align__(16) unsigned short Ps[128 * 64];
  int qt = blockIdx.x, bh = blockIdx.y;
  int b = bh >> 4, h = bh & 15;
  int tid = threadIdx.x, w = tid >> 6, l = tid & 63;
  int g = l >> 4, l15 = l & 15;
  int q0 = qt * 128 + w * 32;

  bf16x8 aq[2][2];  // A-frags of Q: [mi][kk]
  for (int mi = 0; mi < 2; ++mi)
    for (int kk = 0; kk < 2; ++kk) {
      size_t off = ((size_t)(b * SEQ + q0 + mi * 16 + l15) * DM) + h * 64 + kk * 32 + g * 8;
      aq[mi][kk] = *(const bf16x8*)(Q + off);
    }

  float mrow[2][4], lrow[2][4];
  f32x4 oacc[2][4];
  for (int mi = 0; mi < 2; ++mi)
    for (int r = 0; r < 4; ++r) { mrow[mi][r] = -__builtin_inff(); lrow[mi][r] = 0.f; }
  for (int mi = 0; mi < 2; ++mi)
    for (int no = 0; no < 4; ++no)
      for (int e = 0; e < 4; ++e) oacc[mi][no][e] = 0.f;

  int lr8 = l >> 3, lp = l & 7;
  for (int kt = 0; kt < SEQ / 64; ++kt) {
    __syncthreads();
    for (int i = 0; i < 2; ++i) {
      int cs = i * 4 + w;
      int row = cs * 8 + lr8;
      int c = lp ^ lr8;
      async16(Kg + ((size_t)(b * SEQ + kt * 64 + row) * DM + h * 64 + c * 8), &Ks[cs * 512]);
      async16(Vt + ((size_t)(bh * 64 + row) * SEQ + kt * 64 + c * 8), &Vs[cs * 512]);
    }
    __syncthreads();

    // S = Q K^T  (C-frag: col = k-row, row = q)
    f32x4 sacc[2][4];
    for (int mi = 0; mi < 2; ++mi)
      for (int ni = 0; ni < 4; ++ni)
        for (int e = 0; e < 4; ++e) sacc[mi][ni][e] = 0.f;
    for (int ni = 0; ni < 4; ++ni) {
      int row = ni * 16 + l15;
      bf16x8 b0 = *(const bf16x8*)&Ks[row * 64 + (((0 + g) ^ (row & 7)) * 8)];
      bf16x8 b1 = *(const bf16x8*)&Ks[row * 64 + (((4 + g) ^ (row & 7)) * 8)];
      for (int mi = 0; mi < 2; ++mi) {
        sacc[mi][ni] = __builtin_amdgcn_mfma_f32_16x16x32_bf16(aq[mi][0], b0, sacc[mi][ni], 0, 0, 0);
        sacc[mi][ni] = __builtin_amdgcn_mfma_f32_16x16x32_bf16(aq[mi][1], b1, sacc[mi][ni], 0, 0, 0);
      }
    }
    // online softmax (rows spread over 16-lane groups; reduce with shfl_xor 1..8)
    for (int mi = 0; mi < 2; ++mi)
      for (int ni = 0; ni < 4; ++ni)
        for (int e = 0; e < 4; ++e) sacc[mi][ni][e] *= 0.125f;
    for (int mi = 0; mi < 2; ++mi) {
      for (int r = 0; r < 4; ++r) {
        float mx = fmaxf(fmaxf(sacc[mi][0][r], sacc[mi][1][r]),
                         fmaxf(sacc[mi][2][r], sacc[mi][3][r]));
        for (int off = 1; off < 16; off <<= 1) mx = fmaxf(mx, __shfl_xor(mx, off));
        float mn = fmaxf(mrow[mi][r], mx);
        float co = __expf(mrow[mi][r] - mn);
        float s = 0.f;
        for (int ni = 0; ni < 4; ++ni) {
          float p = __expf(sacc[mi][ni][r] - mn);
          sacc[mi][ni][r] = p;
          s += p;
        }
        for (int off = 1; off < 16; off <<= 1) s += __shfl_xor(s, off);
        lrow[mi][r] = lrow[mi][r] * co + s;
        mrow[mi][r] = mn;
        for (int no = 0; no < 4; ++no) oacc[mi][no][r] *= co;
      }
    }
    // P: C-layout -> swizzled LDS -> A-layout
    for (int mi = 0; mi < 2; ++mi)
      for (int ni = 0; ni < 4; ++ni)
        for (int r = 0; r < 4; ++r) {
          int row = w * 32 + mi * 16 + g * 4 + r;
          int col = ni * 16 + l15;
          Ps[row * 64 + (col ^ ((row & 7) << 3))] = f2bf(sacc[mi][ni][r]);
        }
    __syncthreads();
    // O += P V   (A = P rows, B = Vt rows)
    for (int kk = 0; kk < 2; ++kk) {
      bf16x8 pa[2];
      for (int mi = 0; mi < 2; ++mi) {
        int row = w * 32 + mi * 16 + l15;
        pa[mi] = *(const bf16x8*)&Ps[row * 64 + (((kk * 4 + g) * 8) ^ ((row & 7) << 3))];
      }
      for (int no = 0; no < 4; ++no) {
        int row = no * 16 + l15;
        bf16x8 bv = *(const bf16x8*)&Vs[row * 64 + (((kk * 4 + g) ^ (row & 7)) * 8)];
        for (int mi = 0; mi < 2; ++mi)
          oacc[mi][no] = __builtin_amdgcn_mfma_f32_16x16x32_bf16(pa[mi], bv, oacc[mi][no], 0, 0, 0);
      }
    }
  }
  for (int mi = 0; mi < 2; ++mi)
    for (int r = 0; r < 4; ++r) {
      float inv = 1.f / lrow[mi][r];
      int srow = q0 + mi * 16 + g * 4 + r;
      for (int no = 0; no < 4; ++no) {
        int col = h * 64 + no * 16 + l15;
        Og[(size_t)(b * SEQ + srow) * DM + col] = f2bf(oacc[mi][no][r] * inv);
      }
    }
}

extern "C" void kernel_launch(void* const* d_in, const int* in_sizes, int n_in,
                              void* d_out, int out_size, void* d_ws, size_t ws_size,
                              hipStream_t stream) {
  const float* x  = (const float*)d_in[0];
  const float* wq = (const float*)d_in[1];
  const float* bq = (const float*)d_in[2];
  const float* wk = (const float*)d_in[3];
  const float* bk = (const float*)d_in[4];
  const float* wv = (const float*)d_in[5];
  const float* bv = (const float*)d_in[6];
  const float* wo = (const float*)d_in[7];
  const float* bo = (const float*)d_in[8];

  const size_t SZ_X = (size_t)MTOT * DM * 2;   // 16.78 MB
  const size_t SZ_W = (size_t)DM * DM * 2;     // 2.10 MB
  char* ws = (char*)d_ws;
  size_t off = 0;
  unsigned short* xb  = (unsigned short*)(ws + off); off += SZ_X;
  unsigned short* wqT = (unsigned short*)(ws + off); off += SZ_W;
  unsigned short* wkT = (unsigned short*)(ws + off); off += SZ_W;
  unsigned short* wvT = (unsigned short*)(ws + off); off += SZ_W;
  unsigned short* woT = (unsigned short*)(ws + off); off += SZ_W;
  unsigned short* Qb  = (unsigned short*)(ws + off); off += SZ_X;
  unsigned short* Kb  = (unsigned short*)(ws + off); off += SZ_X;
  unsigned short* Vb  = (unsigned short*)(ws + off); off += SZ_X;
  unsigned short* Vtb = (unsigned short*)(ws + off); off += SZ_X;
  unsigned short* Ab  = (unsigned short*)(ws + off); off += SZ_X;
  if (ws_size < off) return;  // loud failure (zero output) rather than corruption

  k_cvt<<<dim3(4096), dim3(256), 0, stream>>>(x, xb);
  k_wt<<<dim3(16, 16), dim3(256), 0, stream>>>(wq, wqT);
  k_wt<<<dim3(16, 16), dim3(256), 0, stream>>>(wk, wkT);
  k_wt<<<dim3(16, 16), dim3(256), 0, stream>>>(wv, wvT);
  k_wt<<<dim3(16, 16), dim3(256), 0, stream>>>(wo, woT);
  k_gemm<<<dim3(8, 64), dim3(256), 0, stream>>>(xb, wqT, bq, Qb, nullptr);
  k_gemm<<<dim3(8, 64), dim3(256), 0, stream>>>(xb, wkT, bk, Kb, nullptr);
  k_gemm<<<dim3(8, 64), dim3(256), 0, stream>>>(xb, wvT, bv, Vb, nullptr);
  k_vt<<<dim3(32, 64), dim3(256), 0, stream>>>(Vb, Vtb);
  k_attn<<<dim3(16, 64), dim3(256), 0, stream>>>(Qb, Kb, Vtb, Ab);
  k_gemm<<<dim3(8, 64), dim3(256), 0, stream>>>(Ab, woT, bo, nullptr, (float*)d_out);
}

// Round 2
// 223.976 us; speedup vs baseline: 1.5904x; 1.5904x over previous
//
#include <hip/hip_runtime.h>

// MHA forward: B=4 S=2048 D=1024 H=16 dh=64, fp32 in/out, bf16 MFMA compute.
// R2: swapped-QK^T in-lane softmax, exp2+defer-max, 2-phase pipelined attn (1 barrier/tile),
//     packed P writes, fused QKV GEMM launch, fused weight transposes.

typedef __bf16 bf16x8 __attribute__((ext_vector_type(8)));
typedef __bf16 bf16x4 __attribute__((ext_vector_type(4)));
typedef float f32x4 __attribute__((ext_vector_type(4)));
typedef unsigned short u16x8 __attribute__((ext_vector_type(8)));

#define SEQ 2048
#define DM 1024
#define NHEAD 16
#define MTOT 8192  // B*S

__device__ __forceinline__ unsigned short f2bf(float f) {
  unsigned u = __builtin_bit_cast(unsigned, f);
  u += 0x7fffu + ((u >> 16) & 1u);  // RNE
  return (unsigned short)(u >> 16);
}

__device__ __forceinline__ void async16(const void* g, void* l) {
  __builtin_amdgcn_global_load_lds(
      (const __attribute__((address_space(1))) void*)g,
      (__attribute__((address_space(3))) void*)l, 16, 0, 0);
}

// ---------------- x fp32 -> bf16 ----------------
__global__ __launch_bounds__(256) void k_cvt(const float* __restrict__ x,
                                             unsigned short* __restrict__ xb) {
  size_t i = ((size_t)blockIdx.x * 256 + threadIdx.x) * 8;
  float4 a = *(const float4*)(x + i);
  float4 b = *(const float4*)(x + i + 4);
  u16x8 o;
  o[0] = f2bf(a.x); o[1] = f2bf(a.y); o[2] = f2bf(a.z); o[3] = f2bf(a.w);
  o[4] = f2bf(b.x); o[5] = f2bf(b.y); o[6] = f2bf(b.z); o[7] = f2bf(b.w);
  *(u16x8*)(xb + i) = o;
}

// ---------------- weights fp32 [K][N] -> bf16 wt [N][K], 4 matrices in one launch ----------------
__global__ __launch_bounds__(256) void k_wt(const float* __restrict__ w0, const float* __restrict__ w1,
                                            const float* __restrict__ w2, const float* __restrict__ w3,
                                            unsigned short* __restrict__ t0, unsigned short* __restrict__ t1,
                                            unsigned short* __restrict__ t2, unsigned short* __restrict__ t3) {
  __shared__ float t[64][65];
  int z = blockIdx.z;
  const float* w = z == 0 ? w0 : z == 1 ? w1 : z == 2 ? w2 : w3;
  unsigned short* wt = z == 0 ? t0 : z == 1 ? t1 : z == 2 ? t2 : t3;
  int nt = blockIdx.x, kt = blockIdx.y;
  int tx = threadIdx.x & 63, ty = threadIdx.x >> 6;
  for (int i = 0; i < 16; ++i) {
    int r = i * 4 + ty;
    t[r][tx] = w[(size_t)(kt * 64 + r) * DM + nt * 64 + tx];
  }
  __syncthreads();
  for (int i = 0; i < 16; ++i) {
    int r = i * 4 + ty;
    wt[(size_t)(nt * 64 + r) * DM + kt * 64 + tx] = f2bf(t[tx][r]);
  }
}

// ---------------- GEMM body: C[.][1024] = A * Bt^T + bias ----------------
__device__ __forceinline__ void gemm_body(const unsigned short* __restrict__ A,
                                          const unsigned short* __restrict__ Bt,
                                          const float* __restrict__ bias,
                                          unsigned short* __restrict__ Cb,
                                          float* __restrict__ Cf, int bm, int bn) {
  __shared__ __align__(16) unsigned short As[128 * 64];
  __shared__ __align__(16) unsigned short Bs[128 * 64];
  const int K = DM, N = DM;
  int tid = threadIdx.x, w = tid >> 6, l = tid & 63;
  int g = l >> 4, l15 = l & 15;
  int wm = (w >> 1) * 64, wn = (w & 1) * 64;
  f32x4 acc[4][4];
#pragma unroll
  for (int mi = 0; mi < 4; ++mi)
#pragma unroll
    for (int ni = 0; ni < 4; ++ni)
#pragma unroll
      for (int e = 0; e < 4; ++e) acc[mi][ni][e] = 0.f;

  int lr8 = l >> 3, lp = l & 7;
  for (int kt = 0; kt < K / 64; ++kt) {
    __syncthreads();
#pragma unroll
    for (int i = 0; i < 4; ++i) {
      int cs = i * 4 + w;
      int row = cs * 8 + lr8;
      int c = lp ^ lr8;
      async16(A + (size_t)(bm + row) * K + kt * 64 + c * 8, &As[cs * 512]);
      async16(Bt + (size_t)(bn + row) * K + kt * 64 + c * 8, &Bs[cs * 512]);
    }
    __syncthreads();
    bf16x8 af[4][2];
#pragma unroll
    for (int mi = 0; mi < 4; ++mi)
#pragma unroll
      for (int kk = 0; kk < 2; ++kk) {
        int row = wm + mi * 16 + l15;
        af[mi][kk] = *(const bf16x8*)&As[row * 64 + (((kk * 4 + g) ^ (row & 7)) * 8)];
      }
    __builtin_amdgcn_s_setprio(1);
#pragma unroll
    for (int ni = 0; ni < 4; ++ni) {
      int row = wn + ni * 16 + l15;
      bf16x8 b0 = *(const bf16x8*)&Bs[row * 64 + (((0 + g) ^ (row & 7)) * 8)];
      bf16x8 b1 = *(const bf16x8*)&Bs[row * 64 + (((4 + g) ^ (row & 7)) * 8)];
#pragma unroll
      for (int mi = 0; mi < 4; ++mi) {
        acc[mi][ni] = __builtin_amdgcn_mfma_f32_16x16x32_bf16(af[mi][0], b0, acc[mi][ni], 0, 0, 0);
        acc[mi][ni] = __builtin_amdgcn_mfma_f32_16x16x32_bf16(af[mi][1], b1, acc[mi][ni], 0, 0, 0);
      }
    }
    __builtin_amdgcn_s_setprio(0);
  }
  float bv[4];
#pragma unroll
  for (int ni = 0; ni < 4; ++ni) bv[ni] = bias[bn + wn + ni * 16 + l15];
#pragma unroll
  for (int mi = 0; mi < 4; ++mi)
#pragma unroll
    for (int ni = 0; ni < 4; ++ni) {
      int col = bn + wn + ni * 16 + l15;
#pragma unroll
      for (int r = 0; r < 4; ++r) {
        int rowg = bm + wm + mi * 16 + g * 4 + r;
        float v = acc[mi][ni][r] + bv[ni];
        if (Cf) Cf[(size_t)rowg * N + col] = v;
        else    Cb[(size_t)rowg * N + col] = f2bf(v);
      }
    }
}

__global__ __launch_bounds__(256) void k_gemm(const unsigned short* __restrict__ A,
                                              const unsigned short* __restrict__ Bt,
                                              const float* __restrict__ bias,
                                              unsigned short* __restrict__ Cb,
                                              float* __restrict__ Cf) {
  gemm_body(A, Bt, bias, Cb, Cf, blockIdx.y * 128, blockIdx.x * 128);
}

__global__ __launch_bounds__(256) void k_gemm_qkv(const unsigned short* __restrict__ A,
                                                  const unsigned short* bt0, const unsigned short* bt1,
                                                  const unsigned short* bt2,
                                                  const float* b0, const float* b1, const float* b2,
                                                  unsigned short* o0, unsigned short* o1,
                                                  unsigned short* o2) {
  int which = blockIdx.x >> 3;
  const unsigned short* Bt = which == 0 ? bt0 : which == 1 ? bt1 : bt2;
  const float* bias = which == 0 ? b0 : which == 1 ? b1 : b2;
  unsigned short* Cb = which == 0 ? o0 : which == 1 ? o1 : o2;
  gemm_body(A, Bt, bias, Cb, nullptr, blockIdx.y * 128, (blockIdx.x & 7) * 128);
}

// ---------------- V [b][s][h*64+d] -> Vt [bh][d][s] ----------------
__global__ __launch_bounds__(256) void k_vt(const unsigned short* __restrict__ V,
                                            unsigned short* __restrict__ Vt) {
  __shared__ __align__(16) unsigned short t[64 * 64];
  int st = blockIdx.x, bh = blockIdx.y;
  int b = bh >> 4, h = bh & 15;
  int tid = threadIdx.x, w = tid >> 6, l = tid & 63;
  for (int i = 0; i < 2; ++i) {
    int cs = i * 4 + w;
    int row = cs * 8 + (l >> 3);
    int c = l & 7;
    async16(V + ((size_t)(b * SEQ + st * 64 + row) * DM + h * 64 + c * 8), &t[cs * 512]);
  }
  __syncthreads();
  for (int p = 0; p < 2; ++p) {
    int d = p * 32 + (tid >> 3);
    int cs = tid & 7;
    u16x8 o;
    for (int j = 0; j < 8; ++j) o[j] = t[(cs * 8 + j) * 64 + d];
    *(u16x8*)(Vt + ((size_t)bh * 64 + d) * SEQ + st * 64 + cs * 8) = o;
  }
}

// ---------------- flash attention (swapped QK^T, in-lane softmax) ----------------
// grid (16 q-tiles, 64 bh); 4 waves x 32 q-rows; KV tile 64, double-buffered.
__global__ __launch_bounds__(256) void k_attn(const unsigned short* __restrict__ Q,
                                              const unsigned short* __restrict__ Kg,
                                              const unsigned short* __restrict__ Vt,
                                              unsigned short* __restrict__ Og) {
  __shared__ __align__(16) unsigned short Ks[2][64 * 64];
  __shared__ __align__(16) unsigned short Vs[2][64 * 64];
  __shared__ __align__(16) unsigned short Ps[128 * 64];
  const float C = 0.18033688011112042f;  // 0.125 * log2(e)
  const float THR = 44.3614195558365f;   // 8 / C
  int qt = blockIdx.x, bh = blockIdx.y;
  int b = bh >> 4, h = bh & 15;
  int tid = threadIdx.x, w = tid >> 6, l = tid & 63;
  int g = l >> 4, l15 = l & 15, l7 = l15 & 7;
  int q0 = qt * 128 + w * 32;
  int lr8 = l >> 3, lp = l & 7;

  // Q fragments (B-operand of swapped QK^T): rows = q, contiguous dh
  bf16x8 bq[2][2];
#pragma unroll
  for (int qi = 0; qi < 2; ++qi)
#pragma unroll
    for (int kk = 0; kk < 2; ++kk)
      bq[qi][kk] = *(const bf16x8*)(Q + ((size_t)(b * SEQ + q0 + qi * 16 + l15) * DM) +
                                    h * 64 + kk * 32 + g * 8);

  float mrow[2], lrow[2];
  f32x4 oacc[2][4];
#pragma unroll
  for (int qi = 0; qi < 2; ++qi) {
    mrow[qi] = -__builtin_inff();
    lrow[qi] = 0.f;
#pragma unroll
    for (int no = 0; no < 4; ++no)
#pragma unroll
      for (int e = 0; e < 4; ++e) oacc[qi][no][e] = 0.f;
  }

  auto stage = [&](int kt, int bufi) {
#pragma unroll
    for (int i = 0; i < 2; ++i) {
      int cs = i * 4 + w;
      int row = cs * 8 + lr8;
      int c = lp ^ lr8;
      async16(Kg + ((size_t)(b * SEQ + kt * 64 + row) * DM + h * 64 + c * 8), &Ks[bufi][cs * 512]);
      async16(Vt + ((size_t)(bh * 64 + row) * SEQ + kt * 64 + c * 8), &Vs[bufi][cs * 512]);
    }
  };

  stage(0, 0);
  __syncthreads();

  const int NT = SEQ / 64;
  for (int kt = 0; kt < NT; ++kt) {
    int cur = kt & 1;
    if (kt + 1 < NT) stage(kt + 1, cur ^ 1);

    // S^T = K · Q^T : row = k (g*4+r), col = q (l15)
    f32x4 sacc[4][2];
#pragma unroll
    for (int ki = 0; ki < 4; ++ki)
#pragma unroll
      for (int qi = 0; qi < 2; ++qi)
#pragma unroll
        for (int e = 0; e < 4; ++e) sacc[ki][qi][e] = 0.f;
    __builtin_amdgcn_s_setprio(1);
#pragma unroll
    for (int ki = 0; ki < 4; ++ki) {
      int row = ki * 16 + l15;
      bf16x8 a0 = *(const bf16x8*)&Ks[cur][row * 64 + (((0 + g) ^ l7) * 8)];
      bf16x8 a1 = *(const bf16x8*)&Ks[cur][row * 64 + (((4 + g) ^ l7) * 8)];
#pragma unroll
      for (int qi = 0; qi < 2; ++qi) {
        sacc[ki][qi] = __builtin_amdgcn_mfma_f32_16x16x32_bf16(a0, bq[qi][0], sacc[ki][qi], 0, 0, 0);
        sacc[ki][qi] = __builtin_amdgcn_mfma_f32_16x16x32_bf16(a1, bq[qi][1], sacc[ki][qi], 0, 0, 0);
      }
    }
    __builtin_amdgcn_s_setprio(0);

    // online softmax: each lane owns q = qi*16+l15, 16 k-values lane-local
    float mx[2];
#pragma unroll
    for (int qi = 0; qi < 2; ++qi) {
      float m0 = sacc[0][qi][0];
#pragma unroll
      for (int ki = 0; ki < 4; ++ki)
#pragma unroll
        for (int r = 0; r < 4; ++r) m0 = fmaxf(m0, sacc[ki][qi][r]);
      m0 = fmaxf(m0, __shfl_xor(m0, 16));
      m0 = fmaxf(m0, __shfl_xor(m0, 32));
      mx[qi] = m0;
    }
    bool need = (mx[0] > mrow[0] + THR) || (mx[1] > mrow[1] + THR);
    if (__any(need ? 1 : 0)) {
      float co[2];
#pragma unroll
      for (int qi = 0; qi < 2; ++qi) {
        float mn = fmaxf(mrow[qi], mx[qi]);
        co[qi] = __builtin_amdgcn_exp2f((mrow[qi] - mn) * C);
        mrow[qi] = mn;
        lrow[qi] *= co[qi];
      }
#pragma unroll
      for (int qi = 0; qi < 2; ++qi)
#pragma unroll
        for (int r = 0; r < 4; ++r) {
          float bc = __shfl(co[qi], g * 4 + r);
#pragma unroll
          for (int no = 0; no < 4; ++no) oacc[qi][no][r] *= bc;
        }
    }
#pragma unroll
    for (int qi = 0; qi < 2; ++qi) {
      float rs = 0.f;
      int rowg = w * 32 + qi * 16 + l15;
#pragma unroll
      for (int ki = 0; ki < 4; ++ki) {
        float p0 = __builtin_amdgcn_exp2f((sacc[ki][qi][0] - mrow[qi]) * C);
        float p1 = __builtin_amdgcn_exp2f((sacc[ki][qi][1] - mrow[qi]) * C);
        float p2 = __builtin_amdgcn_exp2f((sacc[ki][qi][2] - mrow[qi]) * C);
        float p3 = __builtin_amdgcn_exp2f((sacc[ki][qi][3] - mrow[qi]) * C);
        rs += (p0 + p1) + (p2 + p3);
        bf16x4 pk;
        pk[0] = (__bf16)p0; pk[1] = (__bf16)p1; pk[2] = (__bf16)p2; pk[3] = (__bf16)p3;
        int chunk = ki * 2 + (g >> 1);
        *(bf16x4*)&Ps[rowg * 64 + (((chunk ^ l7) << 3) + ((g & 1) << 2))] = pk;
      }
      rs += __shfl_xor(rs, 16);
      rs += __shfl_xor(rs, 32);
      lrow[qi] += rs;
    }

    // O += P V^T-rows (A = P rows from wave-private Ps slice, B = Vt rows)
#pragma unroll
    for (int kk = 0; kk < 2; ++kk) {
      bf16x8 pa[2];
#pragma unroll
      for (int qi = 0; qi < 2; ++qi) {
        int rowg = w * 32 + qi * 16 + l15;
        pa[qi] = *(const bf16x8*)&Ps[rowg * 64 + (((kk * 4 + g) ^ l7) << 3)];
      }
      __builtin_amdgcn_s_setprio(1);
#pragma unroll
      for (int no = 0; no < 4; ++no) {
        int row = no * 16 + l15;
        bf16x8 bv = *(const bf16x8*)&Vs[cur][row * 64 + (((kk * 4 + g) ^ l7) * 8)];
#pragma unroll
        for (int qi = 0; qi < 2; ++qi)
          oacc[qi][no] = __builtin_amdgcn_mfma_f32_16x16x32_bf16(pa[qi], bv, oacc[qi][no], 0, 0, 0);
      }
      __builtin_amdgcn_s_setprio(0);
    }
    __syncthreads();  // drains vmcnt (stage kt+1) + protects buffer swap
  }

#pragma unroll
  for (int qi = 0; qi < 2; ++qi)
#pragma unroll
    for (int r = 0; r < 4; ++r) {
      float ls = __shfl(lrow[qi], g * 4 + r);
      float inv = 1.f / ls;
      int srow = q0 + qi * 16 + g * 4 + r;
#pragma unroll
      for (int no = 0; no < 4; ++no)
        Og[(size_t)(b * SEQ + srow) * DM + h * 64 + no * 16 + l15] =
            f2bf(oacc[qi][no][r] * inv);
    }
}

extern "C" void kernel_launch(void* const* d_in, const int* in_sizes, int n_in,
                              void* d_out, int out_size, void* d_ws, size_t ws_size,
                              hipStream_t stream) {
  const float* x  = (const float*)d_in[0];
  const float* wq = (const float*)d_in[1];
  const float* bq = (const float*)d_in[2];
  const float* wk = (const float*)d_in[3];
  const float* bk = (const float*)d_in[4];
  const float* wv = (const float*)d_in[5];
  const float* bv = (const float*)d_in[6];
  const float* wo = (const float*)d_in[7];
  const float* bo = (const float*)d_in[8];

  const size_t SZ_X = (size_t)MTOT * DM * 2;
  const size_t SZ_W = (size_t)DM * DM * 2;
  char* ws = (char*)d_ws;
  size_t off = 0;
  unsigned short* xb  = (unsigned short*)(ws + off); off += SZ_X;
  unsigned short* wqT = (unsigned short*)(ws + off); off += SZ_W;
  unsigned short* wkT = (unsigned short*)(ws + off); off += SZ_W;
  unsigned short* wvT = (unsigned short*)(ws + off); off += SZ_W;
  unsigned short* woT = (unsigned short*)(ws + off); off += SZ_W;
  unsigned short* Qb  = (unsigned short*)(ws + off); off += SZ_X;
  unsigned short* Kb  = (unsigned short*)(ws + off); off += SZ_X;
  unsigned short* Vb  = (unsigned short*)(ws + off); off += SZ_X;
  unsigned short* Vtb = (unsigned short*)(ws + off); off += SZ_X;
  unsigned short* Ab  = (unsigned short*)(ws + off); off += SZ_X;
  if (ws_size < off) return;

  k_cvt<<<dim3(4096), dim3(256), 0, stream>>>(x, xb);
  k_wt<<<dim3(16, 16, 4), dim3(256), 0, stream>>>(wq, wk, wv, wo, wqT, wkT, wvT, woT);
  k_gemm_qkv<<<dim3(24, 64), dim3(256), 0, stream>>>(xb, wqT, wkT, wvT, bq, bk, bv, Qb, Kb, Vb);
  k_vt<<<dim3(32, 64), dim3(256), 0, stream>>>(Vb, Vtb);
  k_attn<<<dim3(16, 64), dim3(256), 0, stream>>>(Qb, Kb, Vtb, Ab);
  k_gemm<<<dim3(8, 64), dim3(256), 0, stream>>>(Ab, woT, bo, nullptr, (float*)d_out);
}

// Round 3
// 214.273 us; speedup vs baseline: 1.6625x; 1.0453x over previous
//
#include <hip/hip_runtime.h>

// MHA forward: B=4 S=2048 D=1024 H=16 dh=64, fp32 in/out, bf16 MFMA compute.
// R3: attn on mfma_32x32x16 with swapped QK^T -> fully lane-local softmax,
//     in-register P repack (shfl_xor lane<->lane+32 exchange), O^T accumulation,
//     no P LDS bounce, epilogue LDS transpose overlay. GEMM side unchanged.

typedef __bf16 bf16x8 __attribute__((ext_vector_type(8)));
typedef float f32x4 __attribute__((ext_vector_type(4)));
typedef float f32x16 __attribute__((ext_vector_type(16)));
typedef unsigned short u16x8 __attribute__((ext_vector_type(8)));
typedef unsigned u32x4 __attribute__((ext_vector_type(4)));

#define SEQ 2048
#define DM 1024
#define NHEAD 16
#define MTOT 8192  // B*S

__device__ __forceinline__ unsigned short f2bf(float f) {
  unsigned u = __builtin_bit_cast(unsigned, f);
  u += 0x7fffu + ((u >> 16) & 1u);  // RNE
  return (unsigned short)(u >> 16);
}

__device__ __forceinline__ unsigned pkbf(float lo, float hi) {
  __bf16 a = (__bf16)lo, b = (__bf16)hi;  // compiler emits cvt_pk
  return ((unsigned)__builtin_bit_cast(unsigned short, b) << 16) |
         __builtin_bit_cast(unsigned short, a);
}

__device__ __forceinline__ void async16(const void* g, void* l) {
  __builtin_amdgcn_global_load_lds(
      (const __attribute__((address_space(1))) void*)g,
      (__attribute__((address_space(3))) void*)l, 16, 0, 0);
}

// ---------------- x fp32 -> bf16 ----------------
__global__ __launch_bounds__(256) void k_cvt(const float* __restrict__ x,
                                             unsigned short* __restrict__ xb) {
  size_t i = ((size_t)blockIdx.x * 256 + threadIdx.x) * 8;
  float4 a = *(const float4*)(x + i);
  float4 b = *(const float4*)(x + i + 4);
  u16x8 o;
  o[0] = f2bf(a.x); o[1] = f2bf(a.y); o[2] = f2bf(a.z); o[3] = f2bf(a.w);
  o[4] = f2bf(b.x); o[5] = f2bf(b.y); o[6] = f2bf(b.z); o[7] = f2bf(b.w);
  *(u16x8*)(xb + i) = o;
}

// ---------------- weights fp32 [K][N] -> bf16 wt [N][K], 4 in one launch ----------------
__global__ __launch_bounds__(256) void k_wt(const float* __restrict__ w0, const float* __restrict__ w1,
                                            const float* __restrict__ w2, const float* __restrict__ w3,
                                            unsigned short* __restrict__ t0, unsigned short* __restrict__ t1,
                                            unsigned short* __restrict__ t2, unsigned short* __restrict__ t3) {
  __shared__ float t[64][65];
  int z = blockIdx.z;
  const float* w = z == 0 ? w0 : z == 1 ? w1 : z == 2 ? w2 : w3;
  unsigned short* wt = z == 0 ? t0 : z == 1 ? t1 : z == 2 ? t2 : t3;
  int nt = blockIdx.x, kt = blockIdx.y;
  int tx = threadIdx.x & 63, ty = threadIdx.x >> 6;
  for (int i = 0; i < 16; ++i) {
    int r = i * 4 + ty;
    t[r][tx] = w[(size_t)(kt * 64 + r) * DM + nt * 64 + tx];
  }
  __syncthreads();
  for (int i = 0; i < 16; ++i) {
    int r = i * 4 + ty;
    wt[(size_t)(nt * 64 + r) * DM + kt * 64 + tx] = f2bf(t[tx][r]);
  }
}

// ---------------- GEMM body: C[.][1024] = A * Bt^T + bias ----------------
__device__ __forceinline__ void gemm_body(const unsigned short* __restrict__ A,
                                          const unsigned short* __restrict__ Bt,
                                          const float* __restrict__ bias,
                                          unsigned short* __restrict__ Cb,
                                          float* __restrict__ Cf, int bm, int bn) {
  __shared__ __align__(16) unsigned short As[128 * 64];
  __shared__ __align__(16) unsigned short Bs[128 * 64];
  const int K = DM, N = DM;
  int tid = threadIdx.x, w = tid >> 6, l = tid & 63;
  int g = l >> 4, l15 = l & 15;
  int wm = (w >> 1) * 64, wn = (w & 1) * 64;
  f32x4 acc[4][4];
#pragma unroll
  for (int mi = 0; mi < 4; ++mi)
#pragma unroll
    for (int ni = 0; ni < 4; ++ni)
#pragma unroll
      for (int e = 0; e < 4; ++e) acc[mi][ni][e] = 0.f;

  int lr8 = l >> 3, lp = l & 7;
  for (int kt = 0; kt < K / 64; ++kt) {
    __syncthreads();
#pragma unroll
    for (int i = 0; i < 4; ++i) {
      int cs = i * 4 + w;
      int row = cs * 8 + lr8;
      int c = lp ^ lr8;
      async16(A + (size_t)(bm + row) * K + kt * 64 + c * 8, &As[cs * 512]);
      async16(Bt + (size_t)(bn + row) * K + kt * 64 + c * 8, &Bs[cs * 512]);
    }
    __syncthreads();
    bf16x8 af[4][2];
#pragma unroll
    for (int mi = 0; mi < 4; ++mi)
#pragma unroll
      for (int kk = 0; kk < 2; ++kk) {
        int row = wm + mi * 16 + l15;
        af[mi][kk] = *(const bf16x8*)&As[row * 64 + (((kk * 4 + g) ^ (row & 7)) * 8)];
      }
    __builtin_amdgcn_s_setprio(1);
#pragma unroll
    for (int ni = 0; ni < 4; ++ni) {
      int row = wn + ni * 16 + l15;
      bf16x8 b0 = *(const bf16x8*)&Bs[row * 64 + (((0 + g) ^ (row & 7)) * 8)];
      bf16x8 b1 = *(const bf16x8*)&Bs[row * 64 + (((4 + g) ^ (row & 7)) * 8)];
#pragma unroll
      for (int mi = 0; mi < 4; ++mi) {
        acc[mi][ni] = __builtin_amdgcn_mfma_f32_16x16x32_bf16(af[mi][0], b0, acc[mi][ni], 0, 0, 0);
        acc[mi][ni] = __builtin_amdgcn_mfma_f32_16x16x32_bf16(af[mi][1], b1, acc[mi][ni], 0, 0, 0);
      }
    }
    __builtin_amdgcn_s_setprio(0);
  }
  float bv[4];
#pragma unroll
  for (int ni = 0; ni < 4; ++ni) bv[ni] = bias[bn + wn + ni * 16 + l15];
#pragma unroll
  for (int mi = 0; mi < 4; ++mi)
#pragma unroll
    for (int ni = 0; ni < 4; ++ni) {
      int col = bn + wn + ni * 16 + l15;
#pragma unroll
      for (int r = 0; r < 4; ++r) {
        int rowg = bm + wm + mi * 16 + g * 4 + r;
        float v = acc[mi][ni][r] + bv[ni];
        if (Cf) Cf[(size_t)rowg * N + col] = v;
        else    Cb[(size_t)rowg * N + col] = f2bf(v);
      }
    }
}

__global__ __launch_bounds__(256) void k_gemm(const unsigned short* __restrict__ A,
                                              const unsigned short* __restrict__ Bt,
                                              const float* __restrict__ bias,
                                              unsigned short* __restrict__ Cb,
                                              float* __restrict__ Cf) {
  gemm_body(A, Bt, bias, Cb, Cf, blockIdx.y * 128, blockIdx.x * 128);
}

__global__ __launch_bounds__(256) void k_gemm_qkv(const unsigned short* __restrict__ A,
                                                  const unsigned short* bt0, const unsigned short* bt1,
                                                  const unsigned short* bt2,
                                                  const float* b0, const float* b1, const float* b2,
                                                  unsigned short* o0, unsigned short* o1,
                                                  unsigned short* o2) {
  int which = blockIdx.x >> 3;
  const unsigned short* Bt = which == 0 ? bt0 : which == 1 ? bt1 : bt2;
  const float* bias = which == 0 ? b0 : which == 1 ? b1 : b2;
  unsigned short* Cb = which == 0 ? o0 : which == 1 ? o1 : o2;
  gemm_body(A, Bt, bias, Cb, nullptr, blockIdx.y * 128, (blockIdx.x & 7) * 128);
}

// ---------------- V [b][s][h*64+d] -> Vt [bh][d][s] ----------------
__global__ __launch_bounds__(256) void k_vt(const unsigned short* __restrict__ V,
                                            unsigned short* __restrict__ Vt) {
  __shared__ __align__(16) unsigned short t[64 * 64];
  int st = blockIdx.x, bh = blockIdx.y;
  int b = bh >> 4, h = bh & 15;
  int tid = threadIdx.x, w = tid >> 6, l = tid & 63;
  for (int i = 0; i < 2; ++i) {
    int cs = i * 4 + w;
    int row = cs * 8 + (l >> 3);
    int c = l & 7;
    async16(V + ((size_t)(b * SEQ + st * 64 + row) * DM + h * 64 + c * 8), &t[cs * 512]);
  }
  __syncthreads();
  for (int p = 0; p < 2; ++p) {
    int d = p * 32 + (tid >> 3);
    int cs = tid & 7;
    u16x8 o;
    for (int j = 0; j < 8; ++j) o[j] = t[(cs * 8 + j) * 64 + d];
    *(u16x8*)(Vt + ((size_t)bh * 64 + d) * SEQ + st * 64 + cs * 8) = o;
  }
}

// ---------------- flash attention, 32x32x16 MFMA, lane-local softmax ----------------
// grid (16 q-tiles, 64 bh); 4 waves x 32 q-rows; KV tile 64, double-buffered.
__global__ __launch_bounds__(256) void k_attn(const unsigned short* __restrict__ Q,
                                              const unsigned short* __restrict__ Kg,
                                              const unsigned short* __restrict__ Vt,
                                              unsigned short* __restrict__ Og) {
  __shared__ __align__(16) unsigned short smem[16384];  // 32KB: K[2]|V[2]; epilogue overlay
  const float C = 0.18033688011112042f;  // 0.125 * log2(e)
  const float THR = 44.3614195558365f;   // 8 / C
  int qt = blockIdx.x, bh = blockIdx.y;
  int b = bh >> 4, h = bh & 15;
  int tid = threadIdx.x, w = tid >> 6, l = tid & 63;
  int l31 = l & 31, hi = l >> 5, l7 = l & 7;
  int lr8 = l >> 3, lp = l & 7;
  int q0w = qt * 128 + w * 32;
  unsigned short* const ks0 = smem;
  unsigned short* const ks1 = smem + 4096;
  unsigned short* const vs0 = smem + 8192;
  unsigned short* const vs1 = smem + 12288;

  // Q B-frags: lane holds Q[q0w + l31][c*16 + hi*8 .. +7]
  bf16x8 qf[4];
#pragma unroll
  for (int c = 0; c < 4; ++c)
    qf[c] = *(const bf16x8*)(Q + (size_t)(b * SEQ + q0w + l31) * DM + h * 64 + c * 16 + hi * 8);

  float mrow = -__builtin_inff(), lrow = 0.f;
  f32x16 oacc[2];
#pragma unroll
  for (int d = 0; d < 2; ++d)
#pragma unroll
    for (int r = 0; r < 16; ++r) oacc[d][r] = 0.f;

  auto stage = [&](int kt, unsigned short* kdst, unsigned short* vdst) {
#pragma unroll
    for (int i = 0; i < 2; ++i) {
      int cs = i * 4 + w;
      int row = cs * 8 + lr8;
      int c = lp ^ lr8;
      async16(Kg + ((size_t)(b * SEQ + kt * 64 + row) * DM + h * 64 + c * 8), kdst + cs * 512);
      async16(Vt + (((size_t)bh * 64 + row) * SEQ + kt * 64 + c * 8), vdst + cs * 512);
    }
  };

  auto tile = [&](int kt, unsigned short* kc, unsigned short* vc,
                  unsigned short* kn, unsigned short* vn) {
    const int NT = SEQ / 64;
    if (kt + 1 < NT) stage(kt + 1, kn, vn);

    // S^T = K * Q^T : per khalf, C/D col = q = l31, row k' = (r&3)+8*(r>>2)+4*hi
    f32x16 sacc[2];
#pragma unroll
    for (int kh = 0; kh < 2; ++kh)
#pragma unroll
      for (int r = 0; r < 16; ++r) sacc[kh][r] = 0.f;
    __builtin_amdgcn_s_setprio(1);
#pragma unroll
    for (int kh = 0; kh < 2; ++kh) {
      const unsigned short* kbase = kc + (kh * 32 + l31) * 64;
#pragma unroll
      for (int c = 0; c < 4; ++c) {
        bf16x8 a = *(const bf16x8*)(kbase + (((c * 2 + hi) ^ l7) << 3));
        sacc[kh] = __builtin_amdgcn_mfma_f32_32x32x16_bf16(a, qf[c], sacc[kh], 0, 0, 0);
      }
    }
    __builtin_amdgcn_s_setprio(0);

    // lane-local online softmax (lane owns q = l31; halves exchanged via xor-32)
    float mx = sacc[0][0];
#pragma unroll
    for (int kh = 0; kh < 2; ++kh)
#pragma unroll
      for (int r = 0; r < 16; ++r) mx = fmaxf(mx, sacc[kh][r]);
    mx = fmaxf(mx, __shfl_xor(mx, 32));
    if (__any(mx > mrow + THR)) {
      float mn = fmaxf(mrow, mx);
      float co = __builtin_amdgcn_exp2f((mrow - mn) * C);
      lrow *= co;
      mrow = mn;
#pragma unroll
      for (int d = 0; d < 2; ++d)
#pragma unroll
        for (int r = 0; r < 16; ++r) oacc[d][r] *= co;
    }
    float mC = mrow * C;
    float rs = 0.f;
#pragma unroll
    for (int kh = 0; kh < 2; ++kh)
#pragma unroll
      for (int r = 0; r < 16; ++r) {
        float p = __builtin_amdgcn_exp2f(__builtin_fmaf(sacc[kh][r], C, -mC));
        sacc[kh][r] = p;
        rs += p;
      }
    rs += __shfl_xor(rs, 32);
    lrow += rs;

    // P repack: C/D-layout -> B-frags, in-register (lane <-> lane^32 exchange)
    unsigned pw[16];
#pragma unroll
    for (int kh = 0; kh < 2; ++kh)
#pragma unroll
      for (int qd = 0; qd < 4; ++qd) {
        pw[kh * 8 + qd * 2 + 0] = pkbf(sacc[kh][qd * 4 + 0], sacc[kh][qd * 4 + 1]);
        pw[kh * 8 + qd * 2 + 1] = pkbf(sacc[kh][qd * 4 + 2], sacc[kh][qd * 4 + 3]);
      }
    bf16x8 pf[4];
#pragma unroll
    for (int ks = 0; ks < 4; ++ks) {
      int base = (ks >> 1) * 8 + (ks & 1) * 4;
      unsigned A0 = pw[base + 0], A1 = pw[base + 1];
      unsigned B0 = pw[base + 2], B1 = pw[base + 3];
      unsigned sA0 = (unsigned)__shfl_xor((int)A0, 32);
      unsigned sA1 = (unsigned)__shfl_xor((int)A1, 32);
      unsigned sB0 = (unsigned)__shfl_xor((int)B0, 32);
      unsigned sB1 = (unsigned)__shfl_xor((int)B1, 32);
      u32x4 fr;
      fr[0] = hi ? sB0 : A0;
      fr[1] = hi ? sB1 : A1;
      fr[2] = hi ? B0 : sA0;
      fr[3] = hi ? B1 : sA1;
      pf[ks] = __builtin_bit_cast(bf16x8, fr);
    }

    // O^T += V^T * P^T : C/D col = q = l31 (same as softmax state!)
    __builtin_amdgcn_s_setprio(1);
#pragma unroll
    for (int d = 0; d < 2; ++d) {
      const unsigned short* vbase = vc + (d * 32 + l31) * 64;
#pragma unroll
      for (int ks = 0; ks < 4; ++ks) {
        bf16x8 a = *(const bf16x8*)(vbase + (((ks * 2 + hi) ^ l7) << 3));
        oacc[d] = __builtin_amdgcn_mfma_f32_32x32x16_bf16(a, pf[ks], oacc[d], 0, 0, 0);
      }
    }
    __builtin_amdgcn_s_setprio(0);
    __syncthreads();  // drains vmcnt for next stage + protects buffer swap
  };

  stage(0, ks0, vs0);
  __syncthreads();
  for (int kt = 0; kt < SEQ / 64; kt += 2) {
    tile(kt, ks0, vs0, ks1, vs1);
    tile(kt + 1, ks1, vs1, ks0, vs0);
  }

  // epilogue: O^T regs -> per-wave LDS transpose (pad 66) -> coalesced global
  float inv = 1.f / lrow;
  unsigned* ot32 = (unsigned*)(smem + w * (32 * 66));
#pragma unroll
  for (int d = 0; d < 2; ++d)
#pragma unroll
    for (int qd = 0; qd < 4; ++qd) {
      unsigned u0 = pkbf(oacc[d][qd * 4 + 0] * inv, oacc[d][qd * 4 + 1] * inv);
      unsigned u1 = pkbf(oacc[d][qd * 4 + 2] * inv, oacc[d][qd * 4 + 3] * inv);
      int idx = l31 * 33 + d * 16 + qd * 4 + hi * 2;  // u32 units; dh = d*32+qd*8+hi*4
      ot32[idx] = u0;
      ot32[idx + 1] = u1;
    }
  __syncthreads();
  {
    int row = l >> 1, half = l & 1;
    const unsigned* src = ot32 - (w * (32 * 66) / 2) + (w * (32 * 66) / 2);  // same base
    const unsigned* sr = (const unsigned*)(smem + w * (32 * 66)) + row * 33 + half * 16;
    (void)src;
    unsigned o[16];
#pragma unroll
    for (int j = 0; j < 16; ++j) o[j] = sr[j];
    size_t gbase = (size_t)(b * SEQ + q0w + row) * DM + h * 64 + half * 32;
#pragma unroll
    for (int i = 0; i < 4; ++i) {
      u32x4 t;
      t[0] = o[i * 4 + 0]; t[1] = o[i * 4 + 1]; t[2] = o[i * 4 + 2]; t[3] = o[i * 4 + 3];
      *(u32x4*)(Og + gbase + i * 8) = t;
    }
  }
}

extern "C" void kernel_launch(void* const* d_in, const int* in_sizes, int n_in,
                              void* d_out, int out_size, void* d_ws, size_t ws_size,
                              hipStream_t stream) {
  const float* x  = (const float*)d_in[0];
  const float* wq = (const float*)d_in[1];
  const float* bq = (const float*)d_in[2];
  const float* wk = (const float*)d_in[3];
  const float* bk = (const float*)d_in[4];
  const float* wv = (const float*)d_in[5];
  const float* bv = (const float*)d_in[6];
  const float* wo = (const float*)d_in[7];
  const float* bo = (const float*)d_in[8];

  const size_t SZ_X = (size_t)MTOT * DM * 2;
  const size_t SZ_W = (size_t)DM * DM * 2;
  char* ws = (char*)d_ws;
  size_t off = 0;
  unsigned short* xb  = (unsigned short*)(ws + off); off += SZ_X;
  unsigned short* wqT = (unsigned short*)(ws + off); off += SZ_W;
  unsigned short* wkT = (unsigned short*)(ws + off); off += SZ_W;
  unsigned short* wvT = (unsigned short*)(ws + off); off += SZ_W;
  unsigned short* woT = (unsigned short*)(ws + off); off += SZ_W;
  unsigned short* Qb  = (unsigned short*)(ws + off); off += SZ_X;
  unsigned short* Kb  = (unsigned short*)(ws + off); off += SZ_X;
  unsigned short* Vb  = (unsigned short*)(ws + off); off += SZ_X;
  unsigned short* Vtb = (unsigned short*)(ws + off); off += SZ_X;
  unsigned short* Ab  = (unsigned short*)(ws + off); off += SZ_X;
  if (ws_size < off) return;

  k_cvt<<<dim3(4096), dim3(256), 0, stream>>>(x, xb);
  k_wt<<<dim3(16, 16, 4), dim3(256), 0, stream>>>(wq, wk, wv, wo, wqT, wkT, wvT, woT);
  k_gemm_qkv<<<dim3(24, 64), dim3(256), 0, stream>>>(xb, wqT, wkT, wvT, bq, bk, bv, Qb, Kb, Vb);
  k_vt<<<dim3(32, 64), dim3(256), 0, stream>>>(Vb, Vtb);
  k_attn<<<dim3(16, 64), dim3(256), 0, stream>>>(Qb, Kb, Vtb, Ab);
  k_gemm<<<dim3(8, 64), dim3(256), 0, stream>>>(Ab, woT, bo, nullptr, (float*)d_out);
}

// Round 4
// 181.180 us; speedup vs baseline: 1.9661x; 1.1827x over previous
//
#include <hip/hip_runtime.h>

// MHA forward: B=4 S=2048 D=1024 H=16 dh=64, fp32 in/out, bf16 MFMA compute.
// R4: attn with 64 q-rows/wave (halves LDS reads per MFMA), m=0 softmax (scale
//     folded into Q GEMM), permlane32_swap repack (no ds_swizzle), XCD-aware grid.

typedef __bf16 bf16x8 __attribute__((ext_vector_type(8)));
typedef float f32x4 __attribute__((ext_vector_type(4)));
typedef float f32x16 __attribute__((ext_vector_type(16)));
typedef unsigned short u16x8 __attribute__((ext_vector_type(8)));
typedef unsigned u32x4 __attribute__((ext_vector_type(4)));
typedef unsigned u32x2 __attribute__((ext_vector_type(2)));

#define SEQ 2048
#define DM 1024
#define NHEAD 16
#define MTOT 8192  // B*S
#define QSCALE 0.18033688011112042f  // 0.125 * log2(e)

__device__ __forceinline__ unsigned short f2bf(float f) {
  unsigned u = __builtin_bit_cast(unsigned, f);
  u += 0x7fffu + ((u >> 16) & 1u);  // RNE
  return (unsigned short)(u >> 16);
}

__device__ __forceinline__ unsigned pkbf(float lo, float hi) {
  __bf16 a = (__bf16)lo, b = (__bf16)hi;
  return ((unsigned)__builtin_bit_cast(unsigned short, b) << 16) |
         __builtin_bit_cast(unsigned short, a);
}

__device__ __forceinline__ void async16(const void* g, void* l) {
  __builtin_amdgcn_global_load_lds(
      (const __attribute__((address_space(1))) void*)g,
      (__attribute__((address_space(3))) void*)l, 16, 0, 0);
}

// lane<->lane^32 exchange pair (see attn): fr0 = lo?A(own):B(partner), fr2 = lo?A(partner):B(own)
template <bool CX>
__device__ __forceinline__ void exch(unsigned A, unsigned B, unsigned& fr0, unsigned& fr2) {
#if __has_builtin(__builtin_amdgcn_permlane32_swap)
  if constexpr (CX) {
    u32x2 r = __builtin_amdgcn_permlane32_swap(B, A, false, false);
    fr0 = r[1]; fr2 = r[0];
  } else {
    u32x2 r = __builtin_amdgcn_permlane32_swap(A, B, false, false);
    fr0 = r[0]; fr2 = r[1];
  }
#else
  int hi = (threadIdx.x & 63) >> 5;
  unsigned sA = (unsigned)__shfl_xor((int)A, 32);
  unsigned sB = (unsigned)__shfl_xor((int)B, 32);
  fr0 = hi ? sB : A;
  fr2 = hi ? B : sA;
#endif
}

__device__ __forceinline__ float halfsum(float rs) {
#if __has_builtin(__builtin_amdgcn_permlane32_swap)
  unsigned rb = __builtin_bit_cast(unsigned, rs);
  u32x2 rr = __builtin_amdgcn_permlane32_swap(rb, rb, false, false);
  return __builtin_bit_cast(float, rr[0]) + __builtin_bit_cast(float, rr[1]);
#else
  return rs + __shfl_xor(rs, 32);
#endif
}

// ---------------- x fp32 -> bf16 ----------------
__global__ __launch_bounds__(256) void k_cvt(const float* __restrict__ x,
                                             unsigned short* __restrict__ xb) {
  size_t i = ((size_t)blockIdx.x * 256 + threadIdx.x) * 8;
  float4 a = *(const float4*)(x + i);
  float4 b = *(const float4*)(x + i + 4);
  u16x8 o;
  o[0] = f2bf(a.x); o[1] = f2bf(a.y); o[2] = f2bf(a.z); o[3] = f2bf(a.w);
  o[4] = f2bf(b.x); o[5] = f2bf(b.y); o[6] = f2bf(b.z); o[7] = f2bf(b.w);
  *(u16x8*)(xb + i) = o;
}

// ---------------- weights fp32 [K][N] -> bf16 wt [N][K], 4 in one launch ----------------
__global__ __launch_bounds__(256) void k_wt(const float* __restrict__ w0, const float* __restrict__ w1,
                                            const float* __restrict__ w2, const float* __restrict__ w3,
                                            unsigned short* __restrict__ t0, unsigned short* __restrict__ t1,
                                            unsigned short* __restrict__ t2, unsigned short* __restrict__ t3) {
  __shared__ float t[64][65];
  int z = blockIdx.z;
  const float* w = z == 0 ? w0 : z == 1 ? w1 : z == 2 ? w2 : w3;
  unsigned short* wt = z == 0 ? t0 : z == 1 ? t1 : z == 2 ? t2 : t3;
  int nt = blockIdx.x, kt = blockIdx.y;
  int tx = threadIdx.x & 63, ty = threadIdx.x >> 6;
  for (int i = 0; i < 16; ++i) {
    int r = i * 4 + ty;
    t[r][tx] = w[(size_t)(kt * 64 + r) * DM + nt * 64 + tx];
  }
  __syncthreads();
  for (int i = 0; i < 16; ++i) {
    int r = i * 4 + ty;
    wt[(size_t)(nt * 64 + r) * DM + kt * 64 + tx] = f2bf(t[tx][r]);
  }
}

// ---------------- GEMM body: C[.][1024] = (A * Bt^T + bias) * sc ----------------
__device__ __forceinline__ void gemm_body(const unsigned short* __restrict__ A,
                                          const unsigned short* __restrict__ Bt,
                                          const float* __restrict__ bias,
                                          unsigned short* __restrict__ Cb,
                                          float* __restrict__ Cf, int bm, int bn, float sc) {
  __shared__ __align__(16) unsigned short As[128 * 64];
  __shared__ __align__(16) unsigned short Bs[128 * 64];
  const int K = DM, N = DM;
  int tid = threadIdx.x, w = tid >> 6, l = tid & 63;
  int g = l >> 4, l15 = l & 15;
  int wm = (w >> 1) * 64, wn = (w & 1) * 64;
  f32x4 acc[4][4];
#pragma unroll
  for (int mi = 0; mi < 4; ++mi)
#pragma unroll
    for (int ni = 0; ni < 4; ++ni)
#pragma unroll
      for (int e = 0; e < 4; ++e) acc[mi][ni][e] = 0.f;

  int lr8 = l >> 3, lp = l & 7;
  for (int kt = 0; kt < K / 64; ++kt) {
    __syncthreads();
#pragma unroll
    for (int i = 0; i < 4; ++i) {
      int cs = i * 4 + w;
      int row = cs * 8 + lr8;
      int c = lp ^ lr8;
      async16(A + (size_t)(bm + row) * K + kt * 64 + c * 8, &As[cs * 512]);
      async16(Bt + (size_t)(bn + row) * K + kt * 64 + c * 8, &Bs[cs * 512]);
    }
    __syncthreads();
    bf16x8 af[4][2];
#pragma unroll
    for (int mi = 0; mi < 4; ++mi)
#pragma unroll
      for (int kk = 0; kk < 2; ++kk) {
        int row = wm + mi * 16 + l15;
        af[mi][kk] = *(const bf16x8*)&As[row * 64 + (((kk * 4 + g) ^ (row & 7)) * 8)];
      }
    __builtin_amdgcn_s_setprio(1);
#pragma unroll
    for (int ni = 0; ni < 4; ++ni) {
      int row = wn + ni * 16 + l15;
      bf16x8 b0 = *(const bf16x8*)&Bs[row * 64 + (((0 + g) ^ (row & 7)) * 8)];
      bf16x8 b1 = *(const bf16x8*)&Bs[row * 64 + (((4 + g) ^ (row & 7)) * 8)];
#pragma unroll
      for (int mi = 0; mi < 4; ++mi) {
        acc[mi][ni] = __builtin_amdgcn_mfma_f32_16x16x32_bf16(af[mi][0], b0, acc[mi][ni], 0, 0, 0);
        acc[mi][ni] = __builtin_amdgcn_mfma_f32_16x16x32_bf16(af[mi][1], b1, acc[mi][ni], 0, 0, 0);
      }
    }
    __builtin_amdgcn_s_setprio(0);
  }
  float bv[4];
#pragma unroll
  for (int ni = 0; ni < 4; ++ni) bv[ni] = bias[bn + wn + ni * 16 + l15];
#pragma unroll
  for (int mi = 0; mi < 4; ++mi)
#pragma unroll
    for (int ni = 0; ni < 4; ++ni) {
      int col = bn + wn + ni * 16 + l15;
#pragma unroll
      for (int r = 0; r < 4; ++r) {
        int rowg = bm + wm + mi * 16 + g * 4 + r;
        float v = (acc[mi][ni][r] + bv[ni]) * sc;
        if (Cf) Cf[(size_t)rowg * N + col] = v;
        else    Cb[(size_t)rowg * N + col] = f2bf(v);
      }
    }
}

__global__ __launch_bounds__(256) void k_gemm(const unsigned short* __restrict__ A,
                                              const unsigned short* __restrict__ Bt,
                                              const float* __restrict__ bias,
                                              unsigned short* __restrict__ Cb,
                                              float* __restrict__ Cf) {
  gemm_body(A, Bt, bias, Cb, Cf, blockIdx.y * 128, blockIdx.x * 128, 1.f);
}

__global__ __launch_bounds__(256) void k_gemm_qkv(const unsigned short* __restrict__ A,
                                                  const unsigned short* bt0, const unsigned short* bt1,
                                                  const unsigned short* bt2,
                                                  const float* b0, const float* b1, const float* b2,
                                                  unsigned short* o0, unsigned short* o1,
                                                  unsigned short* o2) {
  int which = blockIdx.x >> 3;
  const unsigned short* Bt = which == 0 ? bt0 : which == 1 ? bt1 : bt2;
  const float* bias = which == 0 ? b0 : which == 1 ? b1 : b2;
  unsigned short* Cb = which == 0 ? o0 : which == 1 ? o1 : o2;
  float sc = which == 0 ? QSCALE : 1.f;  // fold 0.125*log2e into Q
  gemm_body(A, Bt, bias, Cb, nullptr, blockIdx.y * 128, (blockIdx.x & 7) * 128, sc);
}

// ---------------- V [b][s][h*64+d] -> Vt [bh][d][s] ----------------
__global__ __launch_bounds__(256) void k_vt(const unsigned short* __restrict__ V,
                                            unsigned short* __restrict__ Vt) {
  __shared__ __align__(16) unsigned short t[64 * 64];
  int st = blockIdx.x, bh = blockIdx.y;
  int b = bh >> 4, h = bh & 15;
  int tid = threadIdx.x, w = tid >> 6, l = tid & 63;
  for (int i = 0; i < 2; ++i) {
    int cs = i * 4 + w;
    int row = cs * 8 + (l >> 3);
    int c = l & 7;
    async16(V + ((size_t)(b * SEQ + st * 64 + row) * DM + h * 64 + c * 8), &t[cs * 512]);
  }
  __syncthreads();
  for (int p = 0; p < 2; ++p) {
    int d = p * 32 + (tid >> 3);
    int cs = tid & 7;
    u16x8 o;
    for (int j = 0; j < 8; ++j) o[j] = t[(cs * 8 + j) * 64 + d];
    *(u16x8*)(Vt + ((size_t)bh * 64 + d) * SEQ + st * 64 + cs * 8) = o;
  }
}

// ---------------- flash attention core (templated on permlane swap convention) ----------------
// 4 waves x 64 q-rows = 256 q/block; KV tile 64 double-buffered; m=0 softmax.
template <bool CX>
__device__ __forceinline__ void attn_core(const unsigned short* __restrict__ Q,
                                          const unsigned short* __restrict__ Kg,
                                          const unsigned short* __restrict__ Vt,
                                          unsigned short* __restrict__ Og,
                                          unsigned short* smem, int b, int h, int bh, int qt) {
  int tid = threadIdx.x, w = tid >> 6, l = tid & 63;
  int l31 = l & 31, hi = l >> 5, l7 = l & 7;
  int lr8 = l >> 3, lp = l & 7;
  int q0w = qt * 256 + w * 64;
  unsigned short* const ks0 = smem;
  unsigned short* const ks1 = smem + 4096;
  unsigned short* const vs0 = smem + 8192;
  unsigned short* const vs1 = smem + 12288;

  // Q B-frags (pre-scaled by QSCALE in GEMM): qf[qh][c] = Q[q0w+qh*32+l31][c*16+hi*8..]
  bf16x8 qf[2][4];
#pragma unroll
  for (int qh = 0; qh < 2; ++qh)
#pragma unroll
    for (int c = 0; c < 4; ++c)
      qf[qh][c] = *(const bf16x8*)(Q + (size_t)(b * SEQ + q0w + qh * 32 + l31) * DM +
                                   h * 64 + c * 16 + hi * 8);

  float lrow[2] = {0.f, 0.f};
  f32x16 oacc[2][2];
#pragma unroll
  for (int qh = 0; qh < 2; ++qh)
#pragma unroll
    for (int d = 0; d < 2; ++d)
#pragma unroll
      for (int r = 0; r < 16; ++r) oacc[qh][d][r] = 0.f;

  auto stage = [&](int kt, unsigned short* kdst, unsigned short* vdst) {
#pragma unroll
    for (int i = 0; i < 2; ++i) {
      int cs = i * 4 + w;
      int row = cs * 8 + lr8;
      int c = lp ^ lr8;
      async16(Kg + ((size_t)(b * SEQ + kt * 64 + row) * DM + h * 64 + c * 8), kdst + cs * 512);
      async16(Vt + (((size_t)bh * 64 + row) * SEQ + kt * 64 + c * 8), vdst + cs * 512);
    }
  };

  auto tile = [&](int kt, unsigned short* kc, unsigned short* vc,
                  unsigned short* kn, unsigned short* vn) {
    if (kt + 1 < SEQ / 64) stage(kt + 1, kn, vn);

    // S^T = K * Q^T : col = q = l31, row k' = (r&3)+8*(r>>2)+4*hi (+kh*32)
    f32x16 sacc[2][2];
#pragma unroll
    for (int qh = 0; qh < 2; ++qh)
#pragma unroll
      for (int kh = 0; kh < 2; ++kh)
#pragma unroll
        for (int r = 0; r < 16; ++r) sacc[qh][kh][r] = 0.f;
    __builtin_amdgcn_s_setprio(1);
#pragma unroll
    for (int kh = 0; kh < 2; ++kh) {
      const unsigned short* kb = kc + (kh * 32 + l31) * 64;
#pragma unroll
      for (int c = 0; c < 4; ++c) {
        bf16x8 a = *(const bf16x8*)(kb + (((2 * c + hi) ^ l7) << 3));
        sacc[0][kh] = __builtin_amdgcn_mfma_f32_32x32x16_bf16(a, qf[0][c], sacc[0][kh], 0, 0, 0);
        sacc[1][kh] = __builtin_amdgcn_mfma_f32_32x32x16_bf16(a, qf[1][c], sacc[1][kh], 0, 0, 0);
      }
    }
    __builtin_amdgcn_s_setprio(0);

    // softmax (m=0): p = exp2(sacc); sum; repack C-layout -> B-frags via permlane
    bf16x8 pf[2][4];
#pragma unroll
    for (int qh = 0; qh < 2; ++qh) {
      float r0 = 0.f, r1 = 0.f, r2 = 0.f, r3 = 0.f;
#pragma unroll
      for (int kh = 0; kh < 2; ++kh)
#pragma unroll
        for (int e = 0; e < 16; e += 4) {
          float p0 = __builtin_amdgcn_exp2f(sacc[qh][kh][e + 0]);
          float p1 = __builtin_amdgcn_exp2f(sacc[qh][kh][e + 1]);
          float p2 = __builtin_amdgcn_exp2f(sacc[qh][kh][e + 2]);
          float p3 = __builtin_amdgcn_exp2f(sacc[qh][kh][e + 3]);
          sacc[qh][kh][e + 0] = p0; sacc[qh][kh][e + 1] = p1;
          sacc[qh][kh][e + 2] = p2; sacc[qh][kh][e + 3] = p3;
          r0 += p0; r1 += p1; r2 += p2; r3 += p3;
        }
      lrow[qh] += halfsum((r0 + r1) + (r2 + r3));
#pragma unroll
      for (int ks = 0; ks < 4; ++ks) {
        int kh = ks >> 1, q4 = (ks & 1) * 8;
        unsigned A0 = pkbf(sacc[qh][kh][q4 + 0], sacc[qh][kh][q4 + 1]);
        unsigned A1 = pkbf(sacc[qh][kh][q4 + 2], sacc[qh][kh][q4 + 3]);
        unsigned B0 = pkbf(sacc[qh][kh][q4 + 4], sacc[qh][kh][q4 + 5]);
        unsigned B1 = pkbf(sacc[qh][kh][q4 + 6], sacc[qh][kh][q4 + 7]);
        unsigned f0, f1, f2, f3;
        exch<CX>(A0, B0, f0, f2);
        exch<CX>(A1, B1, f1, f3);
        u32x4 fr; fr[0] = f0; fr[1] = f1; fr[2] = f2; fr[3] = f3;
        pf[qh][ks] = __builtin_bit_cast(bf16x8, fr);
      }
    }

    // O^T += V^T * P^T
    __builtin_amdgcn_s_setprio(1);
#pragma unroll
    for (int d = 0; d < 2; ++d) {
      const unsigned short* vb = vc + (d * 32 + l31) * 64;
#pragma unroll
      for (int ks = 0; ks < 4; ++ks) {
        bf16x8 a = *(const bf16x8*)(vb + (((2 * ks + hi) ^ l7) << 3));
        oacc[0][d] = __builtin_amdgcn_mfma_f32_32x32x16_bf16(a, pf[0][ks], oacc[0][d], 0, 0, 0);
        oacc[1][d] = __builtin_amdgcn_mfma_f32_32x32x16_bf16(a, pf[1][ks], oacc[1][d], 0, 0, 0);
      }
    }
    __builtin_amdgcn_s_setprio(0);
    __syncthreads();
  };

  stage(0, ks0, vs0);
  __syncthreads();
  for (int kt = 0; kt < SEQ / 64; kt += 2) {
    tile(kt, ks0, vs0, ks1, vs1);
    tile(kt + 1, ks1, vs1, ks0, vs0);
  }

  // epilogue: per q-half, O^T regs -> per-wave LDS transpose (pad 33 u32) -> global
  unsigned* ot = (unsigned*)smem + w * (32 * 33);
#pragma unroll
  for (int qh = 0; qh < 2; ++qh) {
    float inv = 1.f / lrow[qh];
#pragma unroll
    for (int d = 0; d < 2; ++d)
#pragma unroll
      for (int qd = 0; qd < 4; ++qd) {
        unsigned u0 = pkbf(oacc[qh][d][qd * 4 + 0] * inv, oacc[qh][d][qd * 4 + 1] * inv);
        unsigned u1 = pkbf(oacc[qh][d][qd * 4 + 2] * inv, oacc[qh][d][qd * 4 + 3] * inv);
        int idx = l31 * 33 + d * 16 + qd * 4 + hi * 2;
        ot[idx] = u0;
        ot[idx + 1] = u1;
      }
    int row = l >> 1, half = l & 1;
    const unsigned* sr = (const unsigned*)smem + w * (32 * 33) + row * 33 + half * 16;
    unsigned o[16];
#pragma unroll
    for (int j = 0; j < 16; ++j) o[j] = sr[j];
    size_t gbase = (size_t)(b * SEQ + q0w + qh * 32 + row) * DM + h * 64 + half * 32;
#pragma unroll
    for (int i = 0; i < 4; ++i) {
      u32x4 t;
      t[0] = o[i * 4 + 0]; t[1] = o[i * 4 + 1]; t[2] = o[i * 4 + 2]; t[3] = o[i * 4 + 3];
      *(u32x4*)(Og + gbase * 1 + i * 8) = t;
    }
  }
}

__global__ __launch_bounds__(256, 2) void k_attn(const unsigned short* __restrict__ Q,
                                                 const unsigned short* __restrict__ Kg,
                                                 const unsigned short* __restrict__ Vt,
                                                 unsigned short* __restrict__ Og) {
  __shared__ __align__(16) unsigned short smem[16384];  // 32 KB
  int bh = blockIdx.x, qt = blockIdx.y;  // grid(64,8): all q-tiles of a bh on one XCD
  int b = bh >> 4, h = bh & 15;
#if __has_builtin(__builtin_amdgcn_permlane32_swap)
  unsigned lid = threadIdx.x & 63;
  u32x2 pr = __builtin_amdgcn_permlane32_swap(lid, lid + 64u, false, false);
  bool convX = __builtin_amdgcn_readfirstlane(pr[0]) >= 64u;
#else
  bool convX = false;
#endif
  if (convX) attn_core<true>(Q, Kg, Vt, Og, smem, b, h, bh, qt);
  else       attn_core<false>(Q, Kg, Vt, Og, smem, b, h, bh, qt);
}

extern "C" void kernel_launch(void* const* d_in, const int* in_sizes, int n_in,
                              void* d_out, int out_size, void* d_ws, size_t ws_size,
                              hipStream_t stream) {
  const float* x  = (const float*)d_in[0];
  const float* wq = (const float*)d_in[1];
  const float* bq = (const float*)d_in[2];
  const float* wk = (const float*)d_in[3];
  const float* bk = (const float*)d_in[4];
  const float* wv = (const float*)d_in[5];
  const float* bv = (const float*)d_in[6];
  const float* wo = (const float*)d_in[7];
  const float* bo = (const float*)d_in[8];

  const size_t SZ_X = (size_t)MTOT * DM * 2;
  const size_t SZ_W = (size_t)DM * DM * 2;
  char* ws = (char*)d_ws;
  size_t off = 0;
  unsigned short* xb  = (unsigned short*)(ws + off); off += SZ_X;
  unsigned short* wqT = (unsigned short*)(ws + off); off += SZ_W;
  unsigned short* wkT = (unsigned short*)(ws + off); off += SZ_W;
  unsigned short* wvT = (unsigned short*)(ws + off); off += SZ_W;
  unsigned short* woT = (unsigned short*)(ws + off); off += SZ_W;
  unsigned short* Qb  = (unsigned short*)(ws + off); off += SZ_X;
  unsigned short* Kb  = (unsigned short*)(ws + off); off += SZ_X;
  unsigned short* Vb  = (unsigned short*)(ws + off); off += SZ_X;
  unsigned short* Vtb = (unsigned short*)(ws + off); off += SZ_X;
  unsigned short* Ab  = (unsigned short*)(ws + off); off += SZ_X;
  if (ws_size < off) return;

  k_cvt<<<dim3(4096), dim3(256), 0, stream>>>(x, xb);
  k_wt<<<dim3(16, 16, 4), dim3(256), 0, stream>>>(wq, wk, wv, wo, wqT, wkT, wvT, woT);
  k_gemm_qkv<<<dim3(24, 64), dim3(256), 0, stream>>>(xb, wqT, wkT, wvT, bq, bk, bv, Qb, Kb, Vb);
  k_vt<<<dim3(32, 64), dim3(256), 0, stream>>>(Vb, Vtb);
  k_attn<<<dim3(64, 8), dim3(256), 0, stream>>>(Qb, Kb, Vtb, Ab);
  k_gemm<<<dim3(8, 64), dim3(256), 0, stream>>>(Ab, woT, bo, nullptr, (float*)d_out);
}